// Round 16
// baseline (122.403 us; speedup 1.0000x reference)
//
#include <hip/hip_runtime.h>
#include <math.h>

typedef __attribute__((ext_vector_type(8))) short short8;
typedef __attribute__((ext_vector_type(4))) float f32x4;
typedef unsigned short u16;
typedef unsigned long long u64;

#define NNPTS 131072          // B*N*K
#define NQ    8192            // B*N

__device__ __forceinline__ u16 f2bf(float f) {
  unsigned u = __float_as_uint(f);
  u = u + 0x7fffu + ((u >> 16) & 1u);
  return (u16)(u >> 16);
}
__device__ __forceinline__ float bf2f(u16 h) {
  return __uint_as_float(((unsigned)h) << 16);
}
// monotone float->uint key: bigger float <-> bigger key
__device__ __forceinline__ unsigned fkey(float f) {
  unsigned u = __float_as_uint(f);
  return u ^ (((unsigned)((int)u >> 31)) | 0x80000000u);
}

// wave64 max-reduce, pure VALU (DPP): row_shr 1/2/4/8, bcast15, bcast31, readlane 63
__device__ __forceinline__ unsigned wave_max_u32(unsigned v) {
  unsigned t;
  t = (unsigned)__builtin_amdgcn_update_dpp(0, (int)v, 0x111, 0xf, 0xf, true); v = v > t ? v : t;
  t = (unsigned)__builtin_amdgcn_update_dpp(0, (int)v, 0x112, 0xf, 0xf, true); v = v > t ? v : t;
  t = (unsigned)__builtin_amdgcn_update_dpp(0, (int)v, 0x114, 0xf, 0xf, true); v = v > t ? v : t;
  t = (unsigned)__builtin_amdgcn_update_dpp(0, (int)v, 0x118, 0xf, 0xf, true); v = v > t ? v : t;
  t = (unsigned)__builtin_amdgcn_update_dpp(0, (int)v, 0x142, 0xf, 0xf, true); v = v > t ? v : t;
  t = (unsigned)__builtin_amdgcn_update_dpp(0, (int)v, 0x143, 0xf, 0xf, true); v = v > t ? v : t;
  return (unsigned)__builtin_amdgcn_readlane((int)v, 63);
}

// ---------------- MFMA helpers ----------------
__device__ __forceinline__ void zero_acc(f32x4 a[2][4]) {
  #pragma unroll
  for (int mt = 0; mt < 2; ++mt)
    #pragma unroll
    for (int nt = 0; nt < 4; ++nt)
      a[mt][nt] = (f32x4){0.f, 0.f, 0.f, 0.f};
}

__device__ __forceinline__ void load_af(const u16* __restrict__ WB, int m0, int row, int g,
                                        short8 a[2][4]) {
  #pragma unroll
  for (int mt = 0; mt < 2; ++mt)
    #pragma unroll
    for (int kc = 0; kc < 4; ++kc)
      a[mt][kc] = *(const short8*)&WB[(size_t)(m0 + mt*16 + row)*128 + kc*32 + g*8];
}

// same fragment from f32 weights, f2bf'd in-register (bit-identical to prep's bf16)
__device__ __forceinline__ void load_af_f32(const float* __restrict__ W, int m0, int row, int g,
                                            short8 a[2][4]) {
  #pragma unroll
  for (int mt = 0; mt < 2; ++mt)
    #pragma unroll
    for (int kc = 0; kc < 4; ++kc) {
      int base = (m0 + mt*16 + row)*128 + kc*32 + g*8;
      float4 f0 = *(const float4*)&W[base];
      float4 f1 = *(const float4*)&W[base + 4];
      short8 v;
      v[0] = (short)f2bf(f0.x); v[1] = (short)f2bf(f0.y);
      v[2] = (short)f2bf(f0.z); v[3] = (short)f2bf(f0.w);
      v[4] = (short)f2bf(f1.x); v[5] = (short)f2bf(f1.y);
      v[6] = (short)f2bf(f1.z); v[7] = (short)f2bf(f1.w);
      a[mt][kc] = v;
    }
}

__device__ __forceinline__ void gemm64(const short8 a[2][4], const uint4* __restrict__ Xs4,
                                       int row, int g, f32x4 acc[2][4]) {
  #pragma unroll
  for (int kc = 0; kc < 4; ++kc) {
    #pragma unroll
    for (int nt = 0; nt < 4; ++nt) {
      int p = nt*16 + row;
      short8 bfr = *(const short8*)&Xs4[p*16 + ((kc*4 + g) ^ (p & 7))];
      acc[0][nt] = __builtin_amdgcn_mfma_f32_16x16x32_bf16(a[0][kc], bfr, acc[0][nt], 0, 0, 0);
      acc[1][nt] = __builtin_amdgcn_mfma_f32_16x16x32_bf16(a[1][kc], bfr, acc[1][nt], 0, 0, 0);
    }
  }
}

// ---------------- K1: knn (bid<2048) | transpose+3GEMMs (2048..2175) | prep (2176..2303) ----------------
__global__ __launch_bounds__(256) void front_kernel(
    const float* __restrict__ xyz, const float* __restrict__ f,
    const float* __restrict__ wphi, const float* __restrict__ wpsi,
    const float* __restrict__ walpha,
    const float* __restrict__ bphi, const float* __restrict__ bpsi,
    const float* __restrict__ balpha,
    const float* __restrict__ wg1, const float* __restrict__ wg2,
    const float* __restrict__ bg1, const float* __restrict__ bg2,
    const float* __restrict__ wt1, const float* __restrict__ bt1,
    const float* __restrict__ wt2, const float* __restrict__ bt2,
    u16* __restrict__ WfusB, float* __restrict__ c0v,
    float* __restrict__ Wc, float* __restrict__ bc,
    float* __restrict__ linxi, float* __restrict__ psiP, float* __restrict__ alphaP,
    int* __restrict__ idxOut)
{
  __shared__ float sh[8320];                     // knn: xxS[4096] | tgemm: T[64][66] + XsB u16[8192]
  int bid = blockIdx.x, tid = threadIdx.x;

  if (bid < 2048) {
    // ---- KNN: wave per query, 64 lanes x 64 points, med3 insert + DPP reduces ----
    float* xxS = sh;
    int lane = tid & 63, wid = tid >> 6;
    int q = bid*4 + wid;
    int b = q >> 12, n = q & 4095;
    const float* X = xyz + (size_t)b * 12288;
    for (int t = tid; t < 4096; t += 256) {
      float mx = X[t], my = X[4096+t], mz = X[8192+t];
      xxS[t] = __fadd_rn(__fadd_rn(__fmul_rn(mx,mx), __fmul_rn(my,my)), __fmul_rn(mz,mz));
    }
    __syncthreads();
    float qx = X[n], qy = X[4096+n], qz = X[8192+n];
    float xxq = xxS[n];

    float v0=-INFINITY, v1=-INFINITY, v2=-INFINITY, v3=-INFINITY;
    int   i0=0x7fffffff, i1=0x7fffffff, i2=0x7fffffff, i3=0x7fffffff;
    u64 alive = ~0ull;

    #pragma unroll 8
    for (int j = 0; j < 64; ++j) {
      int m = j*64 + lane;
      float mx = X[m], my = X[4096+m], mz = X[8192+m];
      float xxm = xxS[m];
      float dot = __fadd_rn(__fadd_rn(__fmul_rn(qx,mx), __fmul_rn(qy,my)), __fmul_rn(qz,mz));
      float inner = __fmul_rn(-2.0f, dot);
      float dv = __fsub_rn(__fsub_rn(-xxm, inner), xxq);   // exact ref order
      bool c0_=dv>v0, c1_=dv>v1, c2_=dv>v2, c3_=dv>v3;
      int ni1 = c0_ ? i0 : (c1_ ? m : i1);
      int ni2 = c1_ ? i1 : (c2_ ? m : i2);
      int ni3 = c2_ ? i2 : (c3_ ? m : i3);
      i0 = c0_ ? m : i0;
      i1 = ni1; i2 = ni2; i3 = ni3;
      float nv1 = __builtin_amdgcn_fmed3f(dv, v0, v1);
      float nv2 = __builtin_amdgcn_fmed3f(dv, v1, v2);
      float nv3 = __builtin_amdgcn_fmed3f(dv, v2, v3);
      v0 = fmaxf(v0, dv);
      v1 = nv1; v2 = nv2; v3 = nv3;
    }

    int cnt = 4;
    for (int r = 0; r < 16; ++r) {
      unsigned hi = fkey(v0);
      unsigned ghi = wave_max_u32(hi);
      u64 bal = __ballot(hi == ghi);
      unsigned gi;
      if (__builtin_popcountll(bal) == 1) {
        int ln = (int)__builtin_ctzll(bal);
        gi = (unsigned)__builtin_amdgcn_readlane(i0, ln);
      } else {
        unsigned lo = (hi == ghi) ? (0xFFFFFFFFu - (unsigned)i0) : 0u;
        gi = 0xFFFFFFFFu - wave_max_u32(lo);     // lowest-index tie-break, exact
      }
      if (lane == 0) idxOut[(size_t)q*16 + r] = (int)gi;
      if ((int)(gi & 63) == lane) {
        alive &= ~(1ull << (gi >> 6));
        v0=v1; i0=i1; v1=v2; i1=i2; v2=v3; i2=i3; v3=-INFINITY; i3=0x7fffffff;
        if (--cnt == 0 && r < 15) {
          v0=v1=v2=v3=-INFINITY; i0=i1=i2=i3=0x7fffffff;
          for (int j2 = 0; j2 < 64; ++j2) {
            if (!((alive >> j2) & 1ull)) continue;
            int m = j2*64 + lane;
            float mx = X[m], my = X[4096+m], mz = X[8192+m];
            float xxm = xxS[m];
            float dot = __fadd_rn(__fadd_rn(__fmul_rn(qx,mx), __fmul_rn(qy,my)), __fmul_rn(qz,mz));
            float inner = __fmul_rn(-2.0f, dot);
            float dv = __fsub_rn(__fsub_rn(-xxm, inner), xxq);
            bool c0_=dv>v0, c1_=dv>v1, c2_=dv>v2, c3_=dv>v3;
            int ni1 = c0_ ? i0 : (c1_ ? m : i1);
            int ni2 = c1_ ? i1 : (c2_ ? m : i2);
            int ni3 = c2_ ? i2 : (c3_ ? m : i3);
            i0 = c0_ ? m : i0;
            i1 = ni1; i2 = ni2; i3 = ni3;
            float nv1 = __builtin_amdgcn_fmed3f(dv, v0, v1);
            float nv2 = __builtin_amdgcn_fmed3f(dv, v1, v2);
            float nv3 = __builtin_amdgcn_fmed3f(dv, v2, v3);
            v0 = fmaxf(v0, dv);
            v1 = nv1; v2 = nv2; v3 = nv3;
          }
          cnt = 4;
        }
      }
    }
  } else if (bid < 2176) {
    // ---- fused transpose + 3 point-GEMMs for 64 points ----
    float (*T)[66] = (float(*)[66])sh;           // 64 x 66 floats
    u16* XsB = (u16*)&sh[4224];                  // swizzled bf16 tile 64x128
    int pg = bid - 2048;                         // 0..127
    int b = pg >> 6;
    int n0 = (pg & 63) * 64;
    size_t g0 = (size_t)pg * 64;                 // = b*4096 + n0
    int tx = tid & 63, tg = tid >> 6;
    const float* src = f + ((size_t)b * 128) * 4096 + n0;
    #pragma unroll
    for (int half = 0; half < 2; ++half) {
      // coalesced load: 64 channels x 64 points (f32)
      #pragma unroll
      for (int it = 0; it < 16; ++it) {
        int cl = tg + it * 4;                    // channel-local 0..63
        T[cl][tx] = src[(size_t)(half*64 + cl) * 4096 + tx];
      }
      __syncthreads();
      // pack bf16 swizzled: u16 idx = p*128 + ((c>>3)^(p&7))*8 + (c&7)
      for (int u = tid; u < 512; u += 256) {
        int p = u >> 3, s8 = u & 7;
        int seg = half*8 + s8;
        ushort4 w2v[2];
        u16* wv = (u16*)w2v;
        #pragma unroll
        for (int r = 0; r < 8; ++r) wv[r] = f2bf(T[s8*8 + r][p]);
        *(uint4*)&XsB[((size_t)p*16 + (seg ^ (p & 7))) * 8] = *(uint4*)w2v;
      }
      __syncthreads();
    }
    int lane = tid & 63, wid = tid >> 6;
    int row = lane & 15, g = lane >> 4, m0 = wid * 32;
    const float* Ws[3]   = {wphi, wpsi, walpha};
    const float* bs[3]   = {bphi, bpsi, balpha};
    float* outs[3]       = {linxi, psiP, alphaP};
    #pragma unroll
    for (int w = 0; w < 3; ++w) {
      short8 afr[2][4];
      load_af_f32(Ws[w], m0, row, g, afr);
      f32x4 acc[2][4];
      zero_acc(acc);
      gemm64(afr, (const uint4*)XsB, row, g, acc);
      #pragma unroll
      for (int mt = 0; mt < 2; ++mt) {
        int c = m0 + mt*16 + g*4;
        float4 bp = *(const float4*)&bs[w][c];
        const float* bpp = (const float*)&bp;
        #pragma unroll
        for (int nt = 0; nt < 4; ++nt) {
          int p = nt*16 + row;
          float4 v = make_float4(acc[mt][nt][0]+bpp[0], acc[mt][nt][1]+bpp[1],
                                 acc[mt][nt][2]+bpp[2], acc[mt][nt][3]+bpp[3]);
          *(float4*)&outs[w][(g0 + p)*128 + c] = v;
        }
      }
    }
  } else {
    // ---- weight prep (WfusB, c0, Wc, bc only) ----
    int cc = bid - 2176;
    if (tid < 128) {
      int i = tid;
      float s = 0.f;
      for (int t = 0; t < 128; ++t) s = fmaf(wg2[cc*128+t], wg1[t*128+i], s);
      WfusB[cc*128+i] = f2bf(s);
      if (i == 0) {
        float s0 = bg2[cc];
        for (int t = 0; t < 128; ++t) s0 = fmaf(wg2[cc*128+t], bg1[t], s0);
        c0v[cc] = s0;
        for (int j = 0; j < 3; ++j) {
          float a = 0.f;
          for (int t = 0; t < 128; ++t) a = fmaf(wt2[cc*128+t], wt1[t*3+j], a);
          Wc[cc*3+j] = a;
        }
        float bb = bt2[cc];
        for (int t = 0; t < 128; ++t) bb = fmaf(wt2[cc*128+t], bt1[t], bb);
        bc[cc] = bb;
      }
    }
  }
}

// ---------------- theta fold (device helper, identical math everywhere) ----------------
__device__ __forceinline__ void theta_fold_c(const double* __restrict__ stS,
                                             const float* __restrict__ Wc,
                                             const float* __restrict__ bc,
                                             const float* __restrict__ gth,
                                             const float* __restrict__ bth,
                                             int c, float* w0o, float* w1o,
                                             float* w2o, float* bdo)
{
  const double cnt = (double)NNPTS;
  double m0 = stS[0]/cnt, m1 = stS[1]/cnt, m2 = stS[2]/cnt;
  double Pxx = stS[3]/cnt, Pxy = stS[4]/cnt, Pxz = stS[5]/cnt;
  double Pyy = stS[6]/cnt, Pyz = stS[7]/cnt, Pzz = stS[8]/cnt;
  double w0 = Wc[c*3], w1 = Wc[c*3+1], w2 = Wc[c*3+2], bb = bc[c];
  double wm = w0*m0 + w1*m1 + w2*m2;
  double mu = wm + bb;
  double quad = w0*(Pxx*w0 + Pxy*w1 + Pxz*w2)
              + w1*(Pxy*w0 + Pyy*w1 + Pyz*w2)
              + w2*(Pxz*w0 + Pyz*w1 + Pzz*w2);
  double Ex2 = quad + 2.0*bb*wm + bb*bb;
  double var = Ex2 - mu*mu;
  double s = (double)gth[c] / sqrt(var + 1e-5);
  double t = (double)bth[c] - s*mu;
  *w0o = (float)(s*w0);
  *w1o = (float)(s*w1);
  *w2o = (float)(s*w2);
  *bdo = (float)(s*bb + t);
}

// ---------------- pos_stats (own kernel: needs idx complete) ----------------
__global__ __launch_bounds__(256) void pos_kernel(const float* __restrict__ xyz,
                                                  const int* __restrict__ idx,
                                                  double* __restrict__ part)
{
  __shared__ double rd[256];
  int qg = blockIdx.x*256 + threadIdx.x;
  int b = qg >> 12, n = qg & 4095;
  const float* X = xyz + (size_t)b * 12288;
  float qx = X[n], qy = X[4096+n], qz = X[8192+n];
  double l[9] = {0,0,0,0,0,0,0,0,0};
  for (int kk = 0; kk < 16; ++kk) {
    int nb = idx[(size_t)qg*16 + kk];
    float px = qx - X[nb], py = qy - X[4096+nb], pz = qz - X[8192+nb];
    l[0] += px; l[1] += py; l[2] += pz;
    l[3] += (double)px*px; l[4] += (double)px*py; l[5] += (double)px*pz;
    l[6] += (double)py*py; l[7] += (double)py*pz; l[8] += (double)pz*pz;
  }
  for (int j = 0; j < 9; ++j) {
    __syncthreads();
    rd[threadIdx.x] = l[j];
    __syncthreads();
    for (int s = 128; s > 0; s >>= 1) {
      if (threadIdx.x < s) rd[threadIdx.x] += rd[threadIdx.x + s];
      __syncthreads();
    }
    if (threadIdx.x == 0) part[(size_t)blockIdx.x*9 + j] = rd[0];
  }
}

// ---------------- gamma BN stats: stage 1 ----------------
__global__ __launch_bounds__(256) void gamma_part(const float* __restrict__ gs,
                                                  const float* __restrict__ gq,
                                                  double* __restrict__ partS,
                                                  double* __restrict__ partQ)
{
  int c = threadIdx.x & 127;
  int arr = threadIdx.x >> 7;
  int j = blockIdx.x;
  const float* src = arr ? gq : gs;
  double s = 0.0;
  #pragma unroll 8
  for (int bk = j*32; bk < j*32 + 32; ++bk)
    s += src[(size_t)bk*128 + c];
  (arr ? partQ : partS)[(size_t)j*128 + c] = s;
}

// ---------------- fused pass: inline theta fold -> rel0 -> fus GEMM -> g2 bf16 [q][c][k] + stats ----------------
__global__ __launch_bounds__(256) void fused_pass(
    const float* __restrict__ psiP, const float* __restrict__ linxi,
    const int* __restrict__ idx, const float* __restrict__ xyz,
    const u16* __restrict__ WfusB, const float* __restrict__ c0,
    const double* __restrict__ part, const float* __restrict__ Wc,
    const float* __restrict__ bc, const float* __restrict__ gth,
    const float* __restrict__ bth,
    u16* __restrict__ g2W,
    float* __restrict__ gs, float* __restrict__ gq)
{
  __shared__ uint4 XsR[64*16];                 // rel0 bf16, swizzled
  __shared__ float LxS[4][128];
  __shared__ float WdS[4][128];                // wd0,wd1,wd2,bd
  __shared__ float posS[3][64];
  __shared__ int   pidx[64];
  __shared__ float redS[128], redQ[128];
  __shared__ double stS[9];

  int tid = threadIdx.x, lane = tid & 63, wid = tid >> 6;
  int row = lane & 15, g = lane >> 4;
  int m0 = wid * 32;
  int q0 = blockIdx.x * 4, b = q0 >> 12;
  int n0 = q0 & 4095;
  const float* X = xyz + (size_t)b * 12288;
  size_t b12 = (size_t)b << 12;

  if (tid < 64) {
    int q = tid >> 4;
    int nb = idx[(size_t)(q0 + q)*16 + (tid & 15)];
    pidx[tid] = nb;
    int nq = n0 + q;
    posS[0][tid] = X[nq]      - X[nb];
    posS[1][tid] = X[4096+nq] - X[4096+nb];
    posS[2][tid] = X[8192+nq] - X[8192+nb];
  } else if (tid < 73) {
    int j = tid - 64;
    double s = 0.0;
    for (int bk = 0; bk < 32; ++bk) s += part[(size_t)bk*9 + j];
    stS[j] = s;
  }
  for (int u = tid; u < 512; u += 256)
    LxS[u >> 7][u & 127] = linxi[(size_t)q0*128 + u];
  __syncthreads();
  if (tid < 128) {
    float a0, a1, a2, a3;
    theta_fold_c(stS, Wc, bc, gth, bth, tid, &a0, &a1, &a2, &a3);
    WdS[0][tid] = a0; WdS[1][tid] = a1; WdS[2][tid] = a2; WdS[3][tid] = a3;
  }
  __syncthreads();

  // assemble rel0 = linxi - psiP[b12 + pidx] + delta  (bf16 swizzled into XsR)
  #pragma unroll
  for (int it = 0; it < 4; ++it) {
    int u = tid + it*256;
    int p = u >> 4, seg = u & 15;
    int q = p >> 4, cc = seg * 8;
    float p0 = posS[0][p], p1 = posS[1][p], p2 = posS[2][p];
    const float* psir = &psiP[(b12 + (size_t)pidx[p])*128 + cc];
    float ps[8];
    *(float4*)&ps[0] = *(const float4*)&psir[0];
    *(float4*)&ps[4] = *(const float4*)&psir[4];
    ushort4 lohi[2];
    u16* wv = (u16*)lohi;
    #pragma unroll
    for (int r = 0; r < 8; ++r) {
      int c = cc + r;
      float d = fmaf(WdS[2][c], p2, fmaf(WdS[1][c], p1, fmaf(WdS[0][c], p0, WdS[3][c])));
      d = fmaxf(d, 0.f);
      wv[r] = f2bf(LxS[q][c] - ps[r] + d);
    }
    XsR[p*16 + (seg ^ (p & 7))] = *(uint4*)lohi;
  }
  __syncthreads();

  // ---- fused gamma GEMM on rel0 ----
  short8 afr[2][4];
  f32x4 acc[2][4];
  load_af(WfusB, m0, row, g, afr);
  zero_acc(acc);
  gemm64(afr, XsR, row, g, acc);

  // ---- gg = fus + c0 -> global bf16 [q][c][k], + per-block stats partials ----
  #pragma unroll
  for (int mt = 0; mt < 2; ++mt) {
    int c = m0 + mt*16 + g*4;
    float4 c0v = *(const float4*)&c0[c];
    const float* c0p = (const float*)&c0v;
    float sv[4], qv[4];
    #pragma unroll
    for (int r = 0; r < 4; ++r) { sv[r] = 0.f; qv[r] = 0.f; }
    #pragma unroll
    for (int nt = 0; nt < 4; ++nt) {
      size_t gbase = ((size_t)(q0 + nt)*128 + c)*16 + row;
      #pragma unroll
      for (int r = 0; r < 4; ++r) {
        float gg = acc[mt][nt][r] + c0p[r];
        g2W[gbase + (size_t)r*16] = f2bf(gg);
        sv[r] += gg; qv[r] = fmaf(gg, gg, qv[r]);
      }
    }
    #pragma unroll
    for (int r = 0; r < 4; ++r) {
      #pragma unroll
      for (int d = 1; d < 16; d <<= 1) {
        sv[r] += __shfl_xor(sv[r], d);
        qv[r] += __shfl_xor(qv[r], d);
      }
    }
    if (row == 0) {
      *(float4*)&redS[c] = make_float4(sv[0], sv[1], sv[2], sv[3]);
      *(float4*)&redQ[c] = make_float4(qv[0], qv[1], qv[2], qv[3]);
    }
  }
  __syncthreads();
  if (tid < 128) {
    gs[(size_t)blockIdx.x*128 + tid] = redS[tid];
    gq[(size_t)blockIdx.x*128 + tid] = redQ[tid];
  }
}

// ---------------- streaming epilogue: 64 channels x 16 queries per block, arrayless softmax ----------------
__global__ __launch_bounds__(256) void out_kernel(const u16* __restrict__ g2W,
                                                  const float* __restrict__ alphaP,
                                                  const int* __restrict__ idx,
                                                  const float* __restrict__ xyz,
                                                  const double* __restrict__ part,
                                                  const float* __restrict__ Wc,
                                                  const float* __restrict__ bc,
                                                  const float* __restrict__ gth,
                                                  const float* __restrict__ bth,
                                                  const double* __restrict__ partS,
                                                  const double* __restrict__ partQ,
                                                  const float* __restrict__ gga,
                                                  const float* __restrict__ bga,
                                                  float* __restrict__ out)
{
  __shared__ int   pidxO[16][16];
  __shared__ float posO[3][16][16];
  __shared__ float prmS[6][64];                  // s, t, w0, w1, w2, bd
  __shared__ float resS[64][18];
  __shared__ double stS[9];
  int tid = threadIdx.x;
  int cblk = blockIdx.x & 1;
  int qblk = blockIdx.x >> 1;
  int c0 = cblk * 64;
  int lc = tid & 63;
  int c = c0 + lc;
  int qg = tid >> 6;                 // 0..3
  int q0 = qblk * 16;                // 16 queries per block (same b)
  int bb = q0 >> 12;
  int n0 = q0 & 4095;
  size_t bOff = (size_t)bb << 12;
  const float* X = xyz + (size_t)bb * 12288;
  {
    int q = tid >> 4, k = tid & 15;          // all 256 threads: 16 q x 16 k
    int gq = q0 + q;
    int nq = gq & 4095;
    int nb = idx[(size_t)gq*16 + k];
    pidxO[q][k] = nb;
    posO[0][q][k] = X[nq]      - X[nb];
    posO[1][q][k] = X[4096+nq] - X[4096+nb];
    posO[2][q][k] = X[8192+nq] - X[8192+nb];
  }
  if (tid < 9) {
    int j = tid;
    double s = 0.0;
    for (int bk = 0; bk < 32; ++bk) s += part[(size_t)bk*9 + j];
    stS[j] = s;
  }
  __syncthreads();
  if (tid < 64) {
    int cc = c0 + tid;
    double S = 0.0, Q = 0.0;
    #pragma unroll 8
    for (int j = 0; j < 64; ++j) {
      S += partS[(size_t)j*128 + cc];
      Q += partQ[(size_t)j*128 + cc];
    }
    const double cntd = (double)NNPTS;
    double md = S/cntd, vd = Q/cntd - md*md;
    double sd = (double)gga[cc] / sqrt(vd + 1e-5);
    prmS[0][tid] = (float)sd;
    prmS[1][tid] = (float)((double)bga[cc] - sd*md);
    float a0, a1, a2, a3;
    theta_fold_c(stS, Wc, bc, gth, bth, cc, &a0, &a1, &a2, &a3);
    prmS[2][tid] = a0; prmS[3][tid] = a1; prmS[4][tid] = a2; prmS[5][tid] = a3;
  }
  __syncthreads();
  float s  = prmS[0][lc], t   = prmS[1][lc];
  float w0 = prmS[2][lc], w1  = prmS[3][lc];
  float w2 = prmS[4][lc], bdv = prmS[5][lc];
  #pragma unroll
  for (int qi = 0; qi < 4; ++qi) {
    int ql = qi*4 + qg;
    int gq = q0 + ql;
    size_t base2 = ((size_t)gq*128 + c)*16;      // [q][c][k]
    uint4 ga = *(const uint4*)&g2W[base2];
    uint4 gb = *(const uint4*)&g2W[base2 + 8];
    unsigned gw[8] = {ga.x, ga.y, ga.z, ga.w, gb.x, gb.y, gb.z, gb.w};
    float se = 0.f, so = 0.f;
    #pragma unroll
    for (int k = 0; k < 16; ++k) {
      u16 hv = (u16)((gw[k >> 1] >> ((k & 1) * 16)) & 0xFFFFu);
      float rel = fmaxf(fmaf(s, bf2f(hv), t), 0.f);
      float e = expf(rel);                       // rel bounded -> ratio == shifted softmax
      float d = fmaf(w2, posO[2][ql][k], fmaf(w1, posO[1][ql][k], fmaf(w0, posO[0][ql][k], bdv)));
      d = fmaxf(d, 0.f);
      float F = alphaP[(bOff + (size_t)pidxO[ql][k])*128 + c] + d;
      se += e; so = fmaf(e, F, so);
    }
    resS[lc][ql] = so / se;
  }
  __syncthreads();
  if (tid < 128) {
    int lc2 = tid >> 1, half = tid & 1;
    int c2 = c0 + lc2;
    float* dst = &out[(((size_t)bb*128 + c2) << 12) + n0 + half*8];
    float4 v0 = make_float4(resS[lc2][half*8+0], resS[lc2][half*8+1],
                            resS[lc2][half*8+2], resS[lc2][half*8+3]);
    float4 v1 = make_float4(resS[lc2][half*8+4], resS[lc2][half*8+5],
                            resS[lc2][half*8+6], resS[lc2][half*8+7]);
    *(float4*)&dst[0] = v0;
    *(float4*)&dst[4] = v1;
  }
}

extern "C" void kernel_launch(void* const* d_in, const int* in_sizes, int n_in,
                              void* d_out, int out_size, void* d_ws, size_t ws_size,
                              hipStream_t stream)
{
  const float* xyz      = (const float*)d_in[0];
  const float* features = (const float*)d_in[1];
  const float* wt1      = (const float*)d_in[2];
  const float* bt1      = (const float*)d_in[3];
  const float* wt2      = (const float*)d_in[4];
  const float* bt2      = (const float*)d_in[5];
  const float* gth      = (const float*)d_in[6];
  const float* bth      = (const float*)d_in[7];
  const float* wphi     = (const float*)d_in[8];
  const float* bphi     = (const float*)d_in[9];
  const float* wpsi     = (const float*)d_in[10];
  const float* bpsi     = (const float*)d_in[11];
  const float* walpha   = (const float*)d_in[12];
  const float* balpha   = (const float*)d_in[13];
  const float* wg1      = (const float*)d_in[14];
  const float* bg1      = (const float*)d_in[15];
  const float* wg2      = (const float*)d_in[16];
  const float* bg2      = (const float*)d_in[17];
  const float* gga      = (const float*)d_in[18];
  const float* bga      = (const float*)d_in[19];

  char* w = (char*)d_ws;
  size_t off = 0;
  auto take = [&](size_t bytes) -> void* {
    void* p = w + off;
    off = (off + bytes + 255) & ~(size_t)255;
    return p;
  };
  int*    idxW    = (int*)   take((size_t)NQ*16*4);
  float*  linxi   = (float*) take((size_t)NQ*128*4);
  float*  psiP    = (float*) take((size_t)NQ*128*4);
  float*  alphaP  = (float*) take((size_t)NQ*128*4);
  u16*    WfusB   = (u16*)   take(32768);
  float*  c0      = (float*) take(512);
  float*  Wc      = (float*) take(1536);
  float*  bc      = (float*) take(512);
  double* part    = (double*)take(32*9*8);
  float*  gs      = (float*) take((size_t)2048*128*4);
  float*  gq      = (float*) take((size_t)2048*128*4);
  double* partS   = (double*)take((size_t)64*128*8);
  double* partQ   = (double*)take((size_t)64*128*8);
  u16*    g2W     = (u16*)   take((size_t)NNPTS*128*2);
  float*  out     = (float*)d_out;

  front_kernel<<<2304, 256, 0, stream>>>(xyz, features,
      wphi, wpsi, walpha, bphi, bpsi, balpha,
      wg1, wg2, bg1, bg2, wt1, bt1, wt2, bt2,
      WfusB, c0, Wc, bc, linxi, psiP, alphaP, idxW);
  pos_kernel<<<32, 256, 0, stream>>>(xyz, idxW, part);
  fused_pass<<<2048, 256, 0, stream>>>(psiP, linxi, idxW, xyz,
      WfusB, c0, part, Wc, bc, gth, bth, g2W, gs, gq);
  gamma_part<<<64, 256, 0, stream>>>(gs, gq, partS, partQ);
  out_kernel<<<1024, 256, 0, stream>>>(g2W, alphaP, idxW, xyz,
      part, Wc, bc, gth, bth, partS, partQ, gga, bga, out);
}

// Round 17
// 118.764 us; speedup vs baseline: 1.0306x; 1.0306x over previous
//
#include <hip/hip_runtime.h>
#include <math.h>

typedef __attribute__((ext_vector_type(8))) short short8;
typedef __attribute__((ext_vector_type(4))) float f32x4;
typedef unsigned short u16;
typedef unsigned long long u64;

#define NNPTS 131072          // B*N*K
#define NQ    8192            // B*N

__device__ __forceinline__ u16 f2bf(float f) {
  unsigned u = __float_as_uint(f);
  u = u + 0x7fffu + ((u >> 16) & 1u);
  return (u16)(u >> 16);
}
__device__ __forceinline__ float bf2f(u16 h) {
  return __uint_as_float(((unsigned)h) << 16);
}
// monotone float->uint key: bigger float <-> bigger key
__device__ __forceinline__ unsigned fkey(float f) {
  unsigned u = __float_as_uint(f);
  return u ^ (((unsigned)((int)u >> 31)) | 0x80000000u);
}

// wave64 max-reduce, pure VALU (DPP): row_shr 1/2/4/8, bcast15, bcast31, readlane 63
__device__ __forceinline__ unsigned wave_max_u32(unsigned v) {
  unsigned t;
  t = (unsigned)__builtin_amdgcn_update_dpp(0, (int)v, 0x111, 0xf, 0xf, true); v = v > t ? v : t;
  t = (unsigned)__builtin_amdgcn_update_dpp(0, (int)v, 0x112, 0xf, 0xf, true); v = v > t ? v : t;
  t = (unsigned)__builtin_amdgcn_update_dpp(0, (int)v, 0x114, 0xf, 0xf, true); v = v > t ? v : t;
  t = (unsigned)__builtin_amdgcn_update_dpp(0, (int)v, 0x118, 0xf, 0xf, true); v = v > t ? v : t;
  t = (unsigned)__builtin_amdgcn_update_dpp(0, (int)v, 0x142, 0xf, 0xf, true); v = v > t ? v : t;
  t = (unsigned)__builtin_amdgcn_update_dpp(0, (int)v, 0x143, 0xf, 0xf, true); v = v > t ? v : t;
  return (unsigned)__builtin_amdgcn_readlane((int)v, 63);
}

// ---------------- K1: knn (bid<2048) | transpose (2048..2303) | prep (2304..2431) ----------------
__global__ __launch_bounds__(256) void front_kernel(
    const float* __restrict__ xyz, const float* __restrict__ f,
    const float* __restrict__ wphi, const float* __restrict__ wpsi,
    const float* __restrict__ walpha,
    const float* __restrict__ wg1, const float* __restrict__ wg2,
    const float* __restrict__ bg1, const float* __restrict__ bg2,
    const float* __restrict__ wt1, const float* __restrict__ bt1,
    const float* __restrict__ wt2, const float* __restrict__ bt2,
    u16* __restrict__ featB,
    u16* __restrict__ WphiB, u16* __restrict__ WpsiB, u16* __restrict__ WalphaB,
    u16* __restrict__ WfusB, float* __restrict__ c0v,
    float* __restrict__ Wc, float* __restrict__ bc,
    int* __restrict__ idxOut)
{
  __shared__ float sh[4160];                     // union: T[64][65] | xxS[4096]
  int bid = blockIdx.x, tid = threadIdx.x;

  if (bid < 2048) {
    // ---- KNN: wave per query, 64 lanes x 64 points, med3 insert + DPP reduces ----
    float* xxS = sh;
    int lane = tid & 63, wid = tid >> 6;
    int q = bid*4 + wid;
    int b = q >> 12, n = q & 4095;
    const float* X = xyz + (size_t)b * 12288;
    // stage ||xj||^2 once per block (exact ref arithmetic)
    for (int t = tid; t < 4096; t += 256) {
      float mx = X[t], my = X[4096+t], mz = X[8192+t];
      xxS[t] = __fadd_rn(__fadd_rn(__fmul_rn(mx,mx), __fmul_rn(my,my)), __fmul_rn(mz,mz));
    }
    __syncthreads();
    float qx = X[n], qy = X[4096+n], qz = X[8192+n];
    float xxq = xxS[n];

    float v0=-INFINITY, v1=-INFINITY, v2=-INFINITY, v3=-INFINITY;
    int   i0=0x7fffffff, i1=0x7fffffff, i2=0x7fffffff, i3=0x7fffffff;
    u64 alive = ~0ull;

    #pragma unroll 8
    for (int j = 0; j < 64; ++j) {
      int m = j*64 + lane;
      float mx = X[m], my = X[4096+m], mz = X[8192+m];
      float xxm = xxS[m];
      float dot = __fadd_rn(__fadd_rn(__fmul_rn(qx,mx), __fmul_rn(qy,my)), __fmul_rn(qz,mz));
      float inner = __fmul_rn(-2.0f, dot);
      float dv = __fsub_rn(__fsub_rn(-xxm, inner), xxq);   // exact ref order
      bool c0_=dv>v0, c1_=dv>v1, c2_=dv>v2, c3_=dv>v3;
      int ni1 = c0_ ? i0 : (c1_ ? m : i1);
      int ni2 = c1_ ? i1 : (c2_ ? m : i2);
      int ni3 = c2_ ? i2 : (c3_ ? m : i3);
      i0 = c0_ ? m : i0;
      i1 = ni1; i2 = ni2; i3 = ni3;
      float nv1 = __builtin_amdgcn_fmed3f(dv, v0, v1);
      float nv2 = __builtin_amdgcn_fmed3f(dv, v1, v2);
      float nv3 = __builtin_amdgcn_fmed3f(dv, v2, v3);
      v0 = fmaxf(v0, dv);
      v1 = nv1; v2 = nv2; v3 = nv3;
    }

    int cnt = 4;
    for (int r = 0; r < 16; ++r) {
      unsigned hi = fkey(v0);
      unsigned ghi = wave_max_u32(hi);
      u64 bal = __ballot(hi == ghi);
      unsigned gi;
      if (__builtin_popcountll(bal) == 1) {
        int ln = (int)__builtin_ctzll(bal);
        gi = (unsigned)__builtin_amdgcn_readlane(i0, ln);
      } else {
        unsigned lo = (hi == ghi) ? (0xFFFFFFFFu - (unsigned)i0) : 0u;
        gi = 0xFFFFFFFFu - wave_max_u32(lo);     // lowest-index tie-break, exact
      }
      if (lane == 0) idxOut[(size_t)q*16 + r] = (int)gi;
      if ((int)(gi & 63) == lane) {
        alive &= ~(1ull << (gi >> 6));
        v0=v1; i0=i1; v1=v2; i1=i2; v2=v3; i2=i3; v3=-INFINITY; i3=0x7fffffff;
        if (--cnt == 0 && r < 15) {
          // rare: this lane supplied 4 winners -> rebuild from alive set
          v0=v1=v2=v3=-INFINITY; i0=i1=i2=i3=0x7fffffff;
          for (int j2 = 0; j2 < 64; ++j2) {
            if (!((alive >> j2) & 1ull)) continue;
            int m = j2*64 + lane;
            float mx = X[m], my = X[4096+m], mz = X[8192+m];
            float xxm = xxS[m];
            float dot = __fadd_rn(__fadd_rn(__fmul_rn(qx,mx), __fmul_rn(qy,my)), __fmul_rn(qz,mz));
            float inner = __fmul_rn(-2.0f, dot);
            float dv = __fsub_rn(__fsub_rn(-xxm, inner), xxq);
            bool c0_=dv>v0, c1_=dv>v1, c2_=dv>v2, c3_=dv>v3;
            int ni1 = c0_ ? i0 : (c1_ ? m : i1);
            int ni2 = c1_ ? i1 : (c2_ ? m : i2);
            int ni3 = c2_ ? i2 : (c3_ ? m : i3);
            i0 = c0_ ? m : i0;
            i1 = ni1; i2 = ni2; i3 = ni3;
            float nv1 = __builtin_amdgcn_fmed3f(dv, v0, v1);
            float nv2 = __builtin_amdgcn_fmed3f(dv, v1, v2);
            float nv3 = __builtin_amdgcn_fmed3f(dv, v2, v3);
            v0 = fmaxf(v0, dv);
            v1 = nv1; v2 = nv2; v3 = nv3;
          }
          cnt = 4;
        }
      }
    }
  } else if (bid < 2304) {
    // ---- transpose features [B][C][N] -> featB bf16 [B][N][C] ----
    float (*T)[65] = (float(*)[65])sh;
    int t = bid - 2048;
    int tx = tid & 63, tg = tid >> 6;
    int n0 = (t & 63) * 64, c0_ = ((t >> 6) & 1) * 64, b = t >> 7;
    const float* src = f + ((size_t)b * 128 + c0_) * 4096 + n0;
    #pragma unroll
    for (int it = 0; it < 16; ++it) {
      int cl = tg + it * 4;
      T[cl][tx] = src[(size_t)cl * 4096 + tx];
    }
    __syncthreads();
    u16* dst = featB + ((size_t)b * 4096 + n0) * 128 + c0_;
    #pragma unroll
    for (int it = 0; it < 16; ++it) {
      int nl = tg + it * 4;
      dst[(size_t)nl * 128 + tx] = f2bf(T[tx][nl]);
    }
  } else {
    // ---- weight prep ----
    int cc = bid - 2304;
    if (tid < 128) {
      int i = tid;
      WphiB[cc*128+i]   = f2bf(wphi[cc*128+i]);
      WpsiB[cc*128+i]   = f2bf(wpsi[cc*128+i]);
      WalphaB[cc*128+i] = f2bf(walpha[cc*128+i]);
      float s = 0.f;
      for (int t = 0; t < 128; ++t) s = fmaf(wg2[cc*128+t], wg1[t*128+i], s);
      WfusB[cc*128+i] = f2bf(s);
      if (i == 0) {
        float s0 = bg2[cc];
        for (int t = 0; t < 128; ++t) s0 = fmaf(wg2[cc*128+t], bg1[t], s0);
        c0v[cc] = s0;
        for (int j = 0; j < 3; ++j) {
          float a = 0.f;
          for (int t = 0; t < 128; ++t) a = fmaf(wt2[cc*128+t], wt1[t*3+j], a);
          Wc[cc*3+j] = a;
        }
        float bb = bt2[cc];
        for (int t = 0; t < 128; ++t) bb = fmaf(wt2[cc*128+t], bt1[t], bb);
        bc[cc] = bb;
      }
    }
  }
}

// ---------------- theta fold (device helper, identical math everywhere) ----------------
__device__ __forceinline__ void theta_fold_c(const double* __restrict__ stS,
                                             const float* __restrict__ Wc,
                                             const float* __restrict__ bc,
                                             const float* __restrict__ gth,
                                             const float* __restrict__ bth,
                                             int c, float* w0o, float* w1o,
                                             float* w2o, float* bdo)
{
  const double cnt = (double)NNPTS;
  double m0 = stS[0]/cnt, m1 = stS[1]/cnt, m2 = stS[2]/cnt;
  double Pxx = stS[3]/cnt, Pxy = stS[4]/cnt, Pxz = stS[5]/cnt;
  double Pyy = stS[6]/cnt, Pyz = stS[7]/cnt, Pzz = stS[8]/cnt;
  double w0 = Wc[c*3], w1 = Wc[c*3+1], w2 = Wc[c*3+2], bb = bc[c];
  double wm = w0*m0 + w1*m1 + w2*m2;
  double mu = wm + bb;
  double quad = w0*(Pxx*w0 + Pxy*w1 + Pxz*w2)
              + w1*(Pxy*w0 + Pyy*w1 + Pyz*w2)
              + w2*(Pxz*w0 + Pyz*w1 + Pzz*w2);
  double Ex2 = quad + 2.0*bb*wm + bb*bb;
  double var = Ex2 - mu*mu;
  double s = (double)gth[c] / sqrt(var + 1e-5);
  double t = (double)bth[c] - s*mu;
  *w0o = (float)(s*w0);
  *w1o = (float)(s*w1);
  *w2o = (float)(s*w2);
  *bdo = (float)(s*bb + t);
}

// ---------------- MFMA helpers ----------------
__device__ __forceinline__ void zero_acc(f32x4 a[2][4]) {
  #pragma unroll
  for (int mt = 0; mt < 2; ++mt)
    #pragma unroll
    for (int nt = 0; nt < 4; ++nt)
      a[mt][nt] = (f32x4){0.f, 0.f, 0.f, 0.f};
}

__device__ __forceinline__ void load_af(const u16* __restrict__ WB, int m0, int row, int g,
                                        short8 a[2][4]) {
  #pragma unroll
  for (int mt = 0; mt < 2; ++mt)
    #pragma unroll
    for (int kc = 0; kc < 4; ++kc)
      a[mt][kc] = *(const short8*)&WB[(size_t)(m0 + mt*16 + row)*128 + kc*32 + g*8];
}

__device__ __forceinline__ void gemm64(const short8 a[2][4], const uint4* __restrict__ Xs4,
                                       int row, int g, f32x4 acc[2][4]) {
  #pragma unroll
  for (int kc = 0; kc < 4; ++kc) {
    #pragma unroll
    for (int nt = 0; nt < 4; ++nt) {
      int p = nt*16 + row;
      short8 bfr = *(const short8*)&Xs4[p*16 + ((kc*4 + g) ^ (p & 7))];
      acc[0][nt] = __builtin_amdgcn_mfma_f32_16x16x32_bf16(a[0][kc], bfr, acc[0][nt], 0, 0, 0);
      acc[1][nt] = __builtin_amdgcn_mfma_f32_16x16x32_bf16(a[1][kc], bfr, acc[1][nt], 0, 0, 0);
    }
  }
}

// ---------------- K2: point_gemms split 3-way (bid<384) | pos_stats (384..415) ----------------
__global__ __launch_bounds__(256) void mid_kernel(
    const u16* __restrict__ featB,
    const u16* __restrict__ WphiB, const u16* __restrict__ WpsiB,
    const u16* __restrict__ WalphaB,
    const float* __restrict__ bphi, const float* __restrict__ bpsi,
    const float* __restrict__ balpha,
    float* __restrict__ linxi, float* __restrict__ psiP, float* __restrict__ alphaP,
    const float* __restrict__ xyz, const int* __restrict__ idx,
    double* __restrict__ part)
{
  __shared__ uint4 Xs4[64*16];
  __shared__ double rd[256];
  int bid = blockIdx.x, tid = threadIdx.x;

  if (bid < 384) {
    int w = bid >> 7;                 // which weight: 0=phi 1=psi 2=alpha
    int pg = bid & 127;               // point group
    int lane = tid & 63, wid = tid >> 6;
    int row = lane & 15, g = lane >> 4, m0 = wid * 32;
    size_t g0 = (size_t)pg * 64;
    for (int u = tid; u < 1024; u += 256) {
      int p = u >> 4, seg = u & 15;
      Xs4[p*16 + (seg ^ (p & 7))] = *(const uint4*)&featB[(g0 + p)*128 + seg*8];
    }
    __syncthreads();
    const u16* WB     = (w == 0) ? WphiB : (w == 1) ? WpsiB : WalphaB;
    const float* bv   = (w == 0) ? bphi  : (w == 1) ? bpsi  : balpha;
    float* outp       = (w == 0) ? linxi : (w == 1) ? psiP  : alphaP;
    short8 afr[2][4];
    load_af(WB, m0, row, g, afr);
    f32x4 acc[2][4];
    zero_acc(acc);
    gemm64(afr, Xs4, row, g, acc);
    #pragma unroll
    for (int mt = 0; mt < 2; ++mt) {
      int c = m0 + mt*16 + g*4;
      float4 bp = *(const float4*)&bv[c];
      const float* bpp = (const float*)&bp;
      #pragma unroll
      for (int nt = 0; nt < 4; ++nt) {
        int p = nt*16 + row;
        float4 v = make_float4(acc[mt][nt][0]+bpp[0], acc[mt][nt][1]+bpp[1],
                               acc[mt][nt][2]+bpp[2], acc[mt][nt][3]+bpp[3]);
        *(float4*)&outp[(g0 + p)*128 + c] = v;
      }
    }
  } else {
    int bid2 = bid - 384;
    int qg = bid2*256 + tid;
    int b = qg >> 12, n = qg & 4095;
    const float* X = xyz + (size_t)b * 12288;
    float qx = X[n], qy = X[4096+n], qz = X[8192+n];
    double l[9] = {0,0,0,0,0,0,0,0,0};
    for (int kk = 0; kk < 16; ++kk) {
      int nb = idx[(size_t)qg*16 + kk];
      float px = qx - X[nb], py = qy - X[4096+nb], pz = qz - X[8192+nb];
      l[0] += px; l[1] += py; l[2] += pz;
      l[3] += (double)px*px; l[4] += (double)px*py; l[5] += (double)px*pz;
      l[6] += (double)py*py; l[7] += (double)py*pz; l[8] += (double)pz*pz;
    }
    for (int j = 0; j < 9; ++j) {
      __syncthreads();
      rd[tid] = l[j];
      __syncthreads();
      for (int s = 128; s > 0; s >>= 1) {
        if (tid < s) rd[tid] += rd[tid + s];
        __syncthreads();
      }
      if (tid == 0) part[(size_t)bid2*9 + j] = rd[0];
    }
  }
}

// ---------------- gamma BN stats: stage 1 ----------------
__global__ __launch_bounds__(256) void gamma_part(const float* __restrict__ gs,
                                                  const float* __restrict__ gq,
                                                  double* __restrict__ partS,
                                                  double* __restrict__ partQ)
{
  int c = threadIdx.x & 127;
  int arr = threadIdx.x >> 7;
  int j = blockIdx.x;
  const float* src = arr ? gq : gs;
  double s = 0.0;
  #pragma unroll 8
  for (int bk = j*32; bk < j*32 + 32; ++bk)
    s += src[(size_t)bk*128 + c];
  (arr ? partQ : partS)[(size_t)j*128 + c] = s;
}

// ---------------- fused pass: XCD-swizzled blocks; inline theta fold -> rel0 -> fus GEMM -> g2 + stats ----------------
__global__ __launch_bounds__(256) void fused_pass(
    const float* __restrict__ psiP, const float* __restrict__ linxi,
    const int* __restrict__ idx, const float* __restrict__ xyz,
    const u16* __restrict__ WfusB, const float* __restrict__ c0,
    const double* __restrict__ part, const float* __restrict__ Wc,
    const float* __restrict__ bc, const float* __restrict__ gth,
    const float* __restrict__ bth,
    u16* __restrict__ g2W,
    float* __restrict__ gs, float* __restrict__ gq)
{
  __shared__ uint4 XsR[64*16];                 // rel0 bf16, swizzled
  __shared__ float LxS[4][128];
  __shared__ float WdS[4][128];                // wd0,wd1,wd2,bd
  __shared__ float posS[3][64];
  __shared__ int   pidx[64];
  __shared__ float redS[128], redQ[128];
  __shared__ double stS[9];

  int tid = threadIdx.x, lane = tid & 63, wid = tid >> 6;
  int row = lane & 15, g = lane >> 4;
  int m0 = wid * 32;
  // XCD-aware bijective swizzle (2048 % 8 == 0): each XCD gets a contiguous query span
  int swb = (blockIdx.x & 7) * 256 + (blockIdx.x >> 3);
  int q0 = swb * 4, b = q0 >> 12;
  int n0 = q0 & 4095;
  const float* X = xyz + (size_t)b * 12288;
  size_t b12 = (size_t)b << 12;

  if (tid < 64) {
    int q = tid >> 4;
    int nb = idx[(size_t)(q0 + q)*16 + (tid & 15)];
    pidx[tid] = nb;
    int nq = n0 + q;
    posS[0][tid] = X[nq]      - X[nb];
    posS[1][tid] = X[4096+nq] - X[4096+nb];
    posS[2][tid] = X[8192+nq] - X[8192+nb];
  } else if (tid < 73) {
    int j = tid - 64;
    double s = 0.0;
    for (int bk = 0; bk < 32; ++bk) s += part[(size_t)bk*9 + j];
    stS[j] = s;
  }
  for (int u = tid; u < 512; u += 256)
    LxS[u >> 7][u & 127] = linxi[(size_t)q0*128 + u];
  __syncthreads();
  if (tid < 128) {
    float a0, a1, a2, a3;
    theta_fold_c(stS, Wc, bc, gth, bth, tid, &a0, &a1, &a2, &a3);
    WdS[0][tid] = a0; WdS[1][tid] = a1; WdS[2][tid] = a2; WdS[3][tid] = a3;
  }
  __syncthreads();

  // assemble rel0 = linxi - psiP[b12 + pidx] + delta  (bf16 swizzled into XsR)
  #pragma unroll
  for (int it = 0; it < 4; ++it) {
    int u = tid + it*256;
    int p = u >> 4, seg = u & 15;
    int q = p >> 4, cc = seg * 8;
    float p0 = posS[0][p], p1 = posS[1][p], p2 = posS[2][p];
    const float* psir = &psiP[(b12 + (size_t)pidx[p])*128 + cc];
    float ps[8];
    *(float4*)&ps[0] = *(const float4*)&psir[0];
    *(float4*)&ps[4] = *(const float4*)&psir[4];
    ushort4 lohi[2];
    u16* wv = (u16*)lohi;
    #pragma unroll
    for (int r = 0; r < 8; ++r) {
      int c = cc + r;
      float d = fmaf(WdS[2][c], p2, fmaf(WdS[1][c], p1, fmaf(WdS[0][c], p0, WdS[3][c])));
      d = fmaxf(d, 0.f);
      wv[r] = f2bf(LxS[q][c] - ps[r] + d);
    }
    XsR[p*16 + (seg ^ (p & 7))] = *(uint4*)lohi;
  }
  __syncthreads();

  // ---- fused gamma GEMM on rel0 ----
  short8 afr[2][4];
  f32x4 acc[2][4];
  load_af(WfusB, m0, row, g, afr);
  zero_acc(acc);
  gemm64(afr, XsR, row, g, acc);

  // ---- gg = fus + c0 -> global bf16 [q][c][k], + per-block stats partials ----
  #pragma unroll
  for (int mt = 0; mt < 2; ++mt) {
    int c = m0 + mt*16 + g*4;
    float4 c0v = *(const float4*)&c0[c];
    const float* c0p = (const float*)&c0v;
    float sv[4], qv[4];
    #pragma unroll
    for (int r = 0; r < 4; ++r) { sv[r] = 0.f; qv[r] = 0.f; }
    #pragma unroll
    for (int nt = 0; nt < 4; ++nt) {
      size_t gbase = ((size_t)(q0 + nt)*128 + c)*16 + row;
      #pragma unroll
      for (int r = 0; r < 4; ++r) {
        float gg = acc[mt][nt][r] + c0p[r];
        g2W[gbase + (size_t)r*16] = f2bf(gg);
        sv[r] += gg; qv[r] = fmaf(gg, gg, qv[r]);
      }
    }
    #pragma unroll
    for (int r = 0; r < 4; ++r) {
      #pragma unroll
      for (int d = 1; d < 16; d <<= 1) {
        sv[r] += __shfl_xor(sv[r], d);
        qv[r] += __shfl_xor(qv[r], d);
      }
    }
    if (row == 0) {
      *(float4*)&redS[c] = make_float4(sv[0], sv[1], sv[2], sv[3]);
      *(float4*)&redQ[c] = make_float4(qv[0], qv[1], qv[2], qv[3]);
    }
  }
  __syncthreads();
  // write stats at the SWIZZLED row so gamma_part's summation order matches R15 exactly
  if (tid < 128) {
    gs[(size_t)swb*128 + tid] = redS[tid];
    gq[(size_t)swb*128 + tid] = redQ[tid];
  }
}

// ---------------- streaming epilogue: XCD-swizzled; 64 channels x 16 queries per block ----------------
__global__ __launch_bounds__(256) void out_kernel(const u16* __restrict__ g2W,
                                                  const float* __restrict__ alphaP,
                                                  const int* __restrict__ idx,
                                                  const float* __restrict__ xyz,
                                                  const double* __restrict__ part,
                                                  const float* __restrict__ Wc,
                                                  const float* __restrict__ bc,
                                                  const float* __restrict__ gth,
                                                  const float* __restrict__ bth,
                                                  const double* __restrict__ partS,
                                                  const double* __restrict__ partQ,
                                                  const float* __restrict__ gga,
                                                  const float* __restrict__ bga,
                                                  float* __restrict__ out)
{
  __shared__ int   pidxO[16][16];
  __shared__ float posO[3][16][16];
  __shared__ float prmS[6][64];                  // s, t, w0, w1, w2, bd
  __shared__ float resS[64][18];
  __shared__ double stS[9];
  int tid = threadIdx.x;
  // XCD-aware bijective swizzle (1024 % 8 == 0)
  int swb = (blockIdx.x & 7) * 128 + (blockIdx.x >> 3);
  int cblk = swb & 1;
  int qblk = swb >> 1;
  int c0 = cblk * 64;
  int lc = tid & 63;
  int c = c0 + lc;
  int qg = tid >> 6;                 // 0..3
  int q0 = qblk * 16;                // 16 queries per block (same b)
  int bb = q0 >> 12;
  int n0 = q0 & 4095;
  size_t bOff = (size_t)bb << 12;
  const float* X = xyz + (size_t)bb * 12288;
  {
    int q = tid >> 4, k = tid & 15;          // all 256 threads: 16 q x 16 k
    int gq = q0 + q;
    int nq = gq & 4095;
    int nb = idx[(size_t)gq*16 + k];
    pidxO[q][k] = nb;
    posO[0][q][k] = X[nq]      - X[nb];
    posO[1][q][k] = X[4096+nq] - X[4096+nb];
    posO[2][q][k] = X[8192+nq] - X[8192+nb];
  }
  if (tid < 9) {
    int j = tid;
    double s = 0.0;
    for (int bk = 0; bk < 32; ++bk) s += part[(size_t)bk*9 + j];
    stS[j] = s;
  }
  __syncthreads();
  if (tid < 64) {
    int cc = c0 + tid;
    // inline gamma_final (identical summation order)
    double S = 0.0, Q = 0.0;
    #pragma unroll 8
    for (int j = 0; j < 64; ++j) {
      S += partS[(size_t)j*128 + cc];
      Q += partQ[(size_t)j*128 + cc];
    }
    const double cntd = (double)NNPTS;
    double md = S/cntd, vd = Q/cntd - md*md;
    double sd = (double)gga[cc] / sqrt(vd + 1e-5);
    prmS[0][tid] = (float)sd;
    prmS[1][tid] = (float)((double)bga[cc] - sd*md);
    float a0, a1, a2, a3;
    theta_fold_c(stS, Wc, bc, gth, bth, cc, &a0, &a1, &a2, &a3);
    prmS[2][tid] = a0; prmS[3][tid] = a1; prmS[4][tid] = a2; prmS[5][tid] = a3;
  }
  __syncthreads();
  float s  = prmS[0][lc], t   = prmS[1][lc];
  float w0 = prmS[2][lc], w1  = prmS[3][lc];
  float w2 = prmS[4][lc], bdv = prmS[5][lc];
  #pragma unroll
  for (int qi = 0; qi < 4; ++qi) {
    int ql = qi*4 + qg;
    int gq = q0 + ql;
    size_t base2 = ((size_t)gq*128 + c)*16;      // [q][c][k]
    uint4 ga = *(const uint4*)&g2W[base2];
    uint4 gb = *(const uint4*)&g2W[base2 + 8];
    unsigned gw[8] = {ga.x, ga.y, ga.z, ga.w, gb.x, gb.y, gb.z, gb.w};
    float se = 0.f, so = 0.f;
    #pragma unroll
    for (int k = 0; k < 16; ++k) {
      u16 hv = (u16)((gw[k >> 1] >> ((k & 1) * 16)) & 0xFFFFu);
      float rel = fmaxf(fmaf(s, bf2f(hv), t), 0.f);
      float e = expf(rel);                       // rel bounded -> ratio == shifted softmax
      float d = fmaf(w2, posO[2][ql][k], fmaf(w1, posO[1][ql][k], fmaf(w0, posO[0][ql][k], bdv)));
      d = fmaxf(d, 0.f);
      float F = alphaP[(bOff + (size_t)pidxO[ql][k])*128 + c] + d;
      se += e; so = fmaf(e, F, so);
    }
    resS[lc][ql] = so / se;
  }
  __syncthreads();
  // coalesced write: thread -> (c2, half), 8 consecutive n = 32B; pairs fill 64B lines
  if (tid < 128) {
    int lc2 = tid >> 1, half = tid & 1;
    int c2 = c0 + lc2;
    float* dst = &out[(((size_t)bb*128 + c2) << 12) + n0 + half*8];
    float4 v0 = make_float4(resS[lc2][half*8+0], resS[lc2][half*8+1],
                            resS[lc2][half*8+2], resS[lc2][half*8+3]);
    float4 v1 = make_float4(resS[lc2][half*8+4], resS[lc2][half*8+5],
                            resS[lc2][half*8+6], resS[lc2][half*8+7]);
    *(float4*)&dst[0] = v0;
    *(float4*)&dst[4] = v1;
  }
}

extern "C" void kernel_launch(void* const* d_in, const int* in_sizes, int n_in,
                              void* d_out, int out_size, void* d_ws, size_t ws_size,
                              hipStream_t stream)
{
  const float* xyz      = (const float*)d_in[0];
  const float* features = (const float*)d_in[1];
  const float* wt1      = (const float*)d_in[2];
  const float* bt1      = (const float*)d_in[3];
  const float* wt2      = (const float*)d_in[4];
  const float* bt2      = (const float*)d_in[5];
  const float* gth      = (const float*)d_in[6];
  const float* bth      = (const float*)d_in[7];
  const float* wphi     = (const float*)d_in[8];
  const float* bphi     = (const float*)d_in[9];
  const float* wpsi     = (const float*)d_in[10];
  const float* bpsi     = (const float*)d_in[11];
  const float* walpha   = (const float*)d_in[12];
  const float* balpha   = (const float*)d_in[13];
  const float* wg1      = (const float*)d_in[14];
  const float* bg1      = (const float*)d_in[15];
  const float* wg2      = (const float*)d_in[16];
  const float* bg2      = (const float*)d_in[17];
  const float* gga      = (const float*)d_in[18];
  const float* bga      = (const float*)d_in[19];

  char* w = (char*)d_ws;
  size_t off = 0;
  auto take = [&](size_t bytes) -> void* {
    void* p = w + off;
    off = (off + bytes + 255) & ~(size_t)255;
    return p;
  };
  int*    idxW    = (int*)   take((size_t)NQ*16*4);
  u16*    featB   = (u16*)   take((size_t)NQ*128*2);
  float*  linxi   = (float*) take((size_t)NQ*128*4);
  float*  psiP    = (float*) take((size_t)NQ*128*4);
  float*  alphaP  = (float*) take((size_t)NQ*128*4);
  u16*    WphiB   = (u16*)   take(32768);
  u16*    WpsiB   = (u16*)   take(32768);
  u16*    WalphaB = (u16*)   take(32768);
  u16*    WfusB   = (u16*)   take(32768);
  float*  c0      = (float*) take(512);
  float*  Wc      = (float*) take(1536);
  float*  bc      = (float*) take(512);
  double* part    = (double*)take(32*9*8);
  float*  gs      = (float*) take((size_t)2048*128*4);
  float*  gq      = (float*) take((size_t)2048*128*4);
  double* partS   = (double*)take((size_t)64*128*8);
  double* partQ   = (double*)take((size_t)64*128*8);
  u16*    g2W     = (u16*)   take((size_t)NNPTS*128*2);
  float*  out     = (float*)d_out;

  front_kernel<<<2432, 256, 0, stream>>>(xyz, features,
      wphi, wpsi, walpha, wg1, wg2, bg1, bg2, wt1, bt1, wt2, bt2,
      featB, WphiB, WpsiB, WalphaB, WfusB, c0, Wc, bc, idxW);
  mid_kernel<<<416, 256, 0, stream>>>(featB, WphiB, WpsiB, WalphaB,
      bphi, bpsi, balpha, linxi, psiP, alphaP, xyz, idxW, part);
  fused_pass<<<2048, 256, 0, stream>>>(psiP, linxi, idxW, xyz,
      WfusB, c0, part, Wc, bc, gth, bth, g2W, gs, gq);
  gamma_part<<<64, 256, 0, stream>>>(gs, gq, partS, partQ);
  out_kernel<<<1024, 256, 0, stream>>>(g2W, alphaP, idxW, xyz,
      part, Wc, bc, gth, bth, partS, partQ, gga, bga, out);
}